// Round 1
// baseline (1095.177 us; speedup 1.0000x reference)
//
#include <hip/hip_runtime.h>
#include <hip/hip_bf16.h>

#define NNODES 50000
#define NEDGES 800000
#define DD 128
#define EDD 32

#define NT 32          // nodes per block tile in node_kernel
#define LDST 36        // LDS inner stride (floats): 36*4=144B, 16B-aligned rows, 8-way (not 32-way) transpose-write conflicts

__device__ __forceinline__ float fast_sigmoid(float x) {
    return 1.0f / (1.0f + __expf(-x));
}
__device__ __forceinline__ float fast_tanh(float x) {
    // tanh(x) = 1 - 2/(exp(2x)+1); saturates correctly at +/-inf
    return 1.0f - 2.0f / (__expf(2.0f * x) + 1.0f);
}

// One wave (64 lanes) per edge: gather node row of src, atomically add into S[dst];
// lanes 0..31 also add edge features into T[dst].
__global__ __launch_bounds__(256) void scatter_kernel(
    const float* __restrict__ x, const float* __restrict__ ef,
    const int* __restrict__ ei, float* __restrict__ S, float* __restrict__ T)
{
    int e = (int)((blockIdx.x * blockDim.x + threadIdx.x) >> 6);
    int lane = threadIdx.x & 63;
    if (e >= NEDGES) return;
    int src = ei[e];
    int dst = ei[NEDGES + e];
    const float2 v = *reinterpret_cast<const float2*>(&x[(size_t)src * DD + lane * 2]);
    float* sd = &S[(size_t)dst * DD + lane * 2];
    unsafeAtomicAdd(sd, v.x);
    unsafeAtomicAdd(sd + 1, v.y);
    if (lane < EDD) {
        unsafeAtomicAdd(&T[(size_t)dst * EDD + lane], ef[(size_t)e * EDD + lane]);
    }
}

// Fused per-node-tile kernel: conv (S@Wtop + T@Wbot + x@Wskip + biases) -> ReLU -> h
// then GRU: z, r, h_tilde, out = z*H + (1-z)*h_tilde.
// Block: 256 threads; tile NT=32 nodes x 128 cols; thread owns 4 rows x 4 cols.
// LDS layout is K-major: lds[k*LDST + n] so the hot loop reads 4 rows as one float4.
__global__ __launch_bounds__(256) void node_kernel(
    const float* __restrict__ x, const float* __restrict__ H,
    const float* __restrict__ S, const float* __restrict__ T,
    const float* __restrict__ Wmsg, const float* __restrict__ bconv,
    const float* __restrict__ Wskip, const float* __restrict__ bskip,
    const float* __restrict__ Wz, const float* __restrict__ bz,
    const float* __restrict__ Wr, const float* __restrict__ br,
    const float* __restrict__ Wh, const float* __restrict__ bh,
    float* __restrict__ out)
{
    __shared__ __align__(16) float lds[288 * LDST];   // 41.5 KB; reused: [288][NT] conv-in, then [256][NT] xh
    const int tid = threadIdx.x;
    const int n0 = blockIdx.x * NT;
    const int cg = tid & 31;   // column group -> cols 4cg..4cg+3
    const int rg = tid >> 5;   // row group   -> rows 4rg..4rg+3
    const int c0 = cg * 4;
    const int r0 = rg * 4;

    // ---- stage conv input transposed: k=0..127 <- S, 128..159 <- T, 160..287 <- x ----
    for (int idx = tid; idx < NT * DD; idx += 256) {
        int n = idx >> 7, k = idx & 127;
        int gn = n0 + n;
        float vs = (gn < NNODES) ? S[(size_t)gn * DD + k] : 0.0f;
        float vx = (gn < NNODES) ? x[(size_t)gn * DD + k] : 0.0f;
        lds[k * LDST + n] = vs;
        lds[(160 + k) * LDST + n] = vx;
    }
    for (int idx = tid; idx < NT * EDD; idx += 256) {
        int n = idx >> 5, k = idx & 31;
        int gn = n0 + n;
        lds[(128 + k) * LDST + n] = (gn < NNODES) ? T[(size_t)gn * EDD + k] : 0.0f;
    }
    __syncthreads();

    // ---- conv GEMM: acc[r][j] over K=288 ----
    float acc[4][4];
    {
        const float4 bc = *reinterpret_cast<const float4*>(&bconv[c0]);
        const float4 bs = *reinterpret_cast<const float4*>(&bskip[c0]);
        float b[4] = {bc.x + bs.x, bc.y + bs.y, bc.z + bs.z, bc.w + bs.w};
        #pragma unroll
        for (int r = 0; r < 4; r++)
            #pragma unroll
            for (int j = 0; j < 4; j++) acc[r][j] = b[j];
    }
    #pragma unroll 2
    for (int k = 0; k < 160; k++) {
        float4 av = *reinterpret_cast<const float4*>(&lds[k * LDST + r0]);
        float4 wv = *reinterpret_cast<const float4*>(&Wmsg[(size_t)k * DD + c0]);
        float a[4] = {av.x, av.y, av.z, av.w};
        float w[4] = {wv.x, wv.y, wv.z, wv.w};
        #pragma unroll
        for (int r = 0; r < 4; r++)
            #pragma unroll
            for (int j = 0; j < 4; j++) acc[r][j] += a[r] * w[j];
    }
    #pragma unroll 2
    for (int k = 0; k < 128; k++) {
        float4 av = *reinterpret_cast<const float4*>(&lds[(160 + k) * LDST + r0]);
        float4 wv = *reinterpret_cast<const float4*>(&Wskip[(size_t)k * DD + c0]);
        float a[4] = {av.x, av.y, av.z, av.w};
        float w[4] = {wv.x, wv.y, wv.z, wv.w};
        #pragma unroll
        for (int r = 0; r < 4; r++)
            #pragma unroll
            for (int j = 0; j < 4; j++) acc[r][j] += a[r] * w[j];
    }
    __syncthreads();   // conv-input LDS is dead; safe to overwrite

    // ---- write h transposed into lds[0..127][n]; stage H into lds[128..255][n] ----
    #pragma unroll
    for (int r = 0; r < 4; r++)
        #pragma unroll
        for (int j = 0; j < 4; j++) {
            float h = acc[r][j];
            h = h > 0.0f ? h : 0.0f;
            lds[(c0 + j) * LDST + (r0 + r)] = h;
        }
    for (int idx = tid; idx < NT * DD; idx += 256) {
        int n = idx >> 7, k = idx & 127;
        int gn = n0 + n;
        lds[(128 + k) * LDST + n] = (gn < NNODES) ? H[(size_t)gn * DD + k] : 0.0f;
    }
    __syncthreads();

    // ---- z and r gates: K=256 over xh = [h, H] ----
    float az[4][4], ar[4][4];
    {
        const float4 bzv = *reinterpret_cast<const float4*>(&bz[c0]);
        const float4 brv = *reinterpret_cast<const float4*>(&br[c0]);
        float vbz[4] = {bzv.x, bzv.y, bzv.z, bzv.w};
        float vbr[4] = {brv.x, brv.y, brv.z, brv.w};
        #pragma unroll
        for (int r = 0; r < 4; r++)
            #pragma unroll
            for (int j = 0; j < 4; j++) { az[r][j] = vbz[j]; ar[r][j] = vbr[j]; }
    }
    #pragma unroll 2
    for (int k = 0; k < 256; k++) {
        float4 av = *reinterpret_cast<const float4*>(&lds[k * LDST + r0]);
        float4 wzv = *reinterpret_cast<const float4*>(&Wz[(size_t)k * DD + c0]);
        float4 wrv = *reinterpret_cast<const float4*>(&Wr[(size_t)k * DD + c0]);
        float a[4] = {av.x, av.y, av.z, av.w};
        float wz[4] = {wzv.x, wzv.y, wzv.z, wzv.w};
        float wr[4] = {wrv.x, wrv.y, wrv.z, wrv.w};
        #pragma unroll
        for (int r = 0; r < 4; r++)
            #pragma unroll
            for (int j = 0; j < 4; j++) { az[r][j] += a[r] * wz[j]; ar[r][j] += a[r] * wr[j]; }
    }

    // z kept in az; read H into regs; compute r*H
    float Hreg[4][4], rH[4][4];
    #pragma unroll
    for (int r = 0; r < 4; r++)
        #pragma unroll
        for (int j = 0; j < 4; j++) {
            az[r][j] = fast_sigmoid(az[r][j]);
            float rv = fast_sigmoid(ar[r][j]);
            Hreg[r][j] = lds[(128 + c0 + j) * LDST + (r0 + r)];
            rH[r][j] = rv * Hreg[r][j];
        }
    __syncthreads();   // all H reads done before overwrite
    #pragma unroll
    for (int r = 0; r < 4; r++)
        #pragma unroll
        for (int j = 0; j < 4; j++)
            lds[(128 + c0 + j) * LDST + (r0 + r)] = rH[r][j];
    __syncthreads();

    // ---- h_tilde: K=256 over [h, r*H] ----
    float ah[4][4];
    {
        const float4 bhv = *reinterpret_cast<const float4*>(&bh[c0]);
        float vb[4] = {bhv.x, bhv.y, bhv.z, bhv.w};
        #pragma unroll
        for (int r = 0; r < 4; r++)
            #pragma unroll
            for (int j = 0; j < 4; j++) ah[r][j] = vb[j];
    }
    #pragma unroll 2
    for (int k = 0; k < 256; k++) {
        float4 av = *reinterpret_cast<const float4*>(&lds[k * LDST + r0]);
        float4 wv = *reinterpret_cast<const float4*>(&Wh[(size_t)k * DD + c0]);
        float a[4] = {av.x, av.y, av.z, av.w};
        float w[4] = {wv.x, wv.y, wv.z, wv.w};
        #pragma unroll
        for (int r = 0; r < 4; r++)
            #pragma unroll
            for (int j = 0; j < 4; j++) ah[r][j] += a[r] * w[j];
    }

    // ---- epilogue: out = z*H + (1-z)*tanh(ah) ----
    #pragma unroll
    for (int r = 0; r < 4; r++) {
        int gn = n0 + r0 + r;
        if (gn < NNODES) {
            #pragma unroll
            for (int j = 0; j < 4; j++) {
                float ht = fast_tanh(ah[r][j]);
                float z = az[r][j];
                out[(size_t)gn * DD + c0 + j] = z * Hreg[r][j] + (1.0f - z) * ht;
            }
        }
    }
}

extern "C" void kernel_launch(void* const* d_in, const int* in_sizes, int n_in,
                              void* d_out, int out_size, void* d_ws, size_t ws_size,
                              hipStream_t stream) {
    const float* x     = (const float*)d_in[0];
    const float* ef    = (const float*)d_in[1];
    const float* Hst   = (const float*)d_in[2];
    const int*   ei    = (const int*)d_in[3];
    const float* Wmsg  = (const float*)d_in[4];
    const float* bconv = (const float*)d_in[5];
    const float* Wskip = (const float*)d_in[6];
    const float* bskip = (const float*)d_in[7];
    const float* Wz    = (const float*)d_in[8];
    const float* bz    = (const float*)d_in[9];
    const float* Wr    = (const float*)d_in[10];
    const float* br    = (const float*)d_in[11];
    const float* Wh    = (const float*)d_in[12];
    const float* bh    = (const float*)d_in[13];
    float* out = (float*)d_out;

    float* S = (float*)d_ws;                       // [N,128]
    float* T = S + (size_t)NNODES * DD;            // [N,32]

    hipMemsetAsync(d_ws, 0, (size_t)NNODES * (DD + EDD) * sizeof(float), stream);

    // scatter: one wave per edge, 4 waves per block
    int nblocks = (NEDGES + 3) / 4;
    scatter_kernel<<<nblocks, 256, 0, stream>>>(x, ef, ei, S, T);

    int nb2 = (NNODES + NT - 1) / NT;
    node_kernel<<<nb2, 256, 0, stream>>>(x, Hst, S, T, Wmsg, bconv, Wskip, bskip,
                                         Wz, bz, Wr, br, Wh, bh, out);
}

// Round 2
// 697.549 us; speedup vs baseline: 1.5700x; 1.5700x over previous
//
#include <hip/hip_runtime.h>
#include <hip/hip_bf16.h>

#define NNODES 50000
#define NEDGES 800000
#define DD 128
#define EDD 32

#define NT 32          // nodes per block tile in node_kernel
#define LDST 36        // LDS inner stride (floats)

__device__ __forceinline__ float fast_sigmoid(float x) {
    return 1.0f / (1.0f + __expf(-x));
}
__device__ __forceinline__ float fast_tanh(float x) {
    return 1.0f - 2.0f / (__expf(2.0f * x) + 1.0f);
}

// ---------------- CSR build ----------------
__global__ __launch_bounds__(256) void count_kernel(const int* __restrict__ ei,
                                                    int* __restrict__ deg) {
    int e = blockIdx.x * 256 + threadIdx.x;
    if (e < NEDGES) atomicAdd(&deg[ei[NEDGES + e]], 1);
}

// single-block exclusive scan over NNODES degrees -> off[N+1], cursor[N]
__global__ __launch_bounds__(1024) void scan_kernel(const int* __restrict__ deg,
                                                    int* __restrict__ off,
                                                    int* __restrict__ cursor) {
    __shared__ int part[1024];
    const int t = threadIdx.x;
    const int CH = (NNODES + 1023) / 1024;   // 49
    const int base = t * CH;
    int s = 0;
    for (int i = 0; i < CH; i++) {
        int idx = base + i;
        if (idx < NNODES) s += deg[idx];
    }
    part[t] = s;
    __syncthreads();
    for (int d = 1; d < 1024; d <<= 1) {
        int v = 0;
        if (t >= d) v = part[t - d];
        __syncthreads();
        if (t >= d) part[t] += v;
        __syncthreads();
    }
    int run = (t == 0) ? 0 : part[t - 1];    // exclusive
    for (int i = 0; i < CH; i++) {
        int idx = base + i;
        if (idx < NNODES) {
            off[idx] = run;
            cursor[idx] = run;
            run += deg[idx];
        }
    }
    if (t == 1023) off[NNODES] = part[1023];
}

__global__ __launch_bounds__(256) void fill_kernel(const int* __restrict__ ei,
                                                   int* __restrict__ cursor,
                                                   int2* __restrict__ csr) {
    int e = blockIdx.x * 256 + threadIdx.x;
    if (e < NEDGES) {
        int dst = ei[NEDGES + e];
        int p = atomicAdd(&cursor[dst], 1);
        csr[p] = make_int2(ei[e], e);        // (src node, edge id)
    }
}

// ---------------- gather aggregation: one wave per node ----------------
__global__ __launch_bounds__(256) void aggregate_kernel(
    const float* __restrict__ x, const float* __restrict__ ef,
    const int2* __restrict__ csr, const int* __restrict__ off,
    float* __restrict__ S, float* __restrict__ T)
{
    int n = (int)((blockIdx.x * blockDim.x + threadIdx.x) >> 6);
    int lane = threadIdx.x & 63;
    if (n >= NNODES) return;
    int i0 = off[n], i1 = off[n + 1];
    float2 acc = make_float2(0.0f, 0.0f);
    float accT = 0.0f;
    for (int i = i0; i < i1; i++) {
        int2 ce = csr[i];
        const float2 v = *reinterpret_cast<const float2*>(&x[(size_t)ce.x * DD + lane * 2]);
        acc.x += v.x;
        acc.y += v.y;
        if (lane < EDD) accT += ef[(size_t)ce.y * EDD + lane];
    }
    *reinterpret_cast<float2*>(&S[(size_t)n * DD + lane * 2]) = acc;
    if (lane < EDD) T[(size_t)n * EDD + lane] = accT;
}

// ---------------- fused node kernel (unchanged from R1) ----------------
__global__ __launch_bounds__(256) void node_kernel(
    const float* __restrict__ x, const float* __restrict__ H,
    const float* __restrict__ S, const float* __restrict__ T,
    const float* __restrict__ Wmsg, const float* __restrict__ bconv,
    const float* __restrict__ Wskip, const float* __restrict__ bskip,
    const float* __restrict__ Wz, const float* __restrict__ bz,
    const float* __restrict__ Wr, const float* __restrict__ br,
    const float* __restrict__ Wh, const float* __restrict__ bh,
    float* __restrict__ out)
{
    __shared__ __align__(16) float lds[288 * LDST];
    const int tid = threadIdx.x;
    const int n0 = blockIdx.x * NT;
    const int cg = tid & 31;
    const int rg = tid >> 5;
    const int c0 = cg * 4;
    const int r0 = rg * 4;

    for (int idx = tid; idx < NT * DD; idx += 256) {
        int n = idx >> 7, k = idx & 127;
        int gn = n0 + n;
        float vs = (gn < NNODES) ? S[(size_t)gn * DD + k] : 0.0f;
        float vx = (gn < NNODES) ? x[(size_t)gn * DD + k] : 0.0f;
        lds[k * LDST + n] = vs;
        lds[(160 + k) * LDST + n] = vx;
    }
    for (int idx = tid; idx < NT * EDD; idx += 256) {
        int n = idx >> 5, k = idx & 31;
        int gn = n0 + n;
        lds[(128 + k) * LDST + n] = (gn < NNODES) ? T[(size_t)gn * EDD + k] : 0.0f;
    }
    __syncthreads();

    float acc[4][4];
    {
        const float4 bc = *reinterpret_cast<const float4*>(&bconv[c0]);
        const float4 bs = *reinterpret_cast<const float4*>(&bskip[c0]);
        float b[4] = {bc.x + bs.x, bc.y + bs.y, bc.z + bs.z, bc.w + bs.w};
        #pragma unroll
        for (int r = 0; r < 4; r++)
            #pragma unroll
            for (int j = 0; j < 4; j++) acc[r][j] = b[j];
    }
    #pragma unroll 2
    for (int k = 0; k < 160; k++) {
        float4 av = *reinterpret_cast<const float4*>(&lds[k * LDST + r0]);
        float4 wv = *reinterpret_cast<const float4*>(&Wmsg[(size_t)k * DD + c0]);
        float a[4] = {av.x, av.y, av.z, av.w};
        float w[4] = {wv.x, wv.y, wv.z, wv.w};
        #pragma unroll
        for (int r = 0; r < 4; r++)
            #pragma unroll
            for (int j = 0; j < 4; j++) acc[r][j] += a[r] * w[j];
    }
    #pragma unroll 2
    for (int k = 0; k < 128; k++) {
        float4 av = *reinterpret_cast<const float4*>(&lds[(160 + k) * LDST + r0]);
        float4 wv = *reinterpret_cast<const float4*>(&Wskip[(size_t)k * DD + c0]);
        float a[4] = {av.x, av.y, av.z, av.w};
        float w[4] = {wv.x, wv.y, wv.z, wv.w};
        #pragma unroll
        for (int r = 0; r < 4; r++)
            #pragma unroll
            for (int j = 0; j < 4; j++) acc[r][j] += a[r] * w[j];
    }
    __syncthreads();

    #pragma unroll
    for (int r = 0; r < 4; r++)
        #pragma unroll
        for (int j = 0; j < 4; j++) {
            float h = acc[r][j];
            h = h > 0.0f ? h : 0.0f;
            lds[(c0 + j) * LDST + (r0 + r)] = h;
        }
    for (int idx = tid; idx < NT * DD; idx += 256) {
        int n = idx >> 7, k = idx & 127;
        int gn = n0 + n;
        lds[(128 + k) * LDST + n] = (gn < NNODES) ? H[(size_t)gn * DD + k] : 0.0f;
    }
    __syncthreads();

    float az[4][4], ar[4][4];
    {
        const float4 bzv = *reinterpret_cast<const float4*>(&bz[c0]);
        const float4 brv = *reinterpret_cast<const float4*>(&br[c0]);
        float vbz[4] = {bzv.x, bzv.y, bzv.z, bzv.w};
        float vbr[4] = {brv.x, brv.y, brv.z, brv.w};
        #pragma unroll
        for (int r = 0; r < 4; r++)
            #pragma unroll
            for (int j = 0; j < 4; j++) { az[r][j] = vbz[j]; ar[r][j] = vbr[j]; }
    }
    #pragma unroll 2
    for (int k = 0; k < 256; k++) {
        float4 av = *reinterpret_cast<const float4*>(&lds[k * LDST + r0]);
        float4 wzv = *reinterpret_cast<const float4*>(&Wz[(size_t)k * DD + c0]);
        float4 wrv = *reinterpret_cast<const float4*>(&Wr[(size_t)k * DD + c0]);
        float a[4] = {av.x, av.y, av.z, av.w};
        float wz[4] = {wzv.x, wzv.y, wzv.z, wzv.w};
        float wr[4] = {wrv.x, wrv.y, wrv.z, wrv.w};
        #pragma unroll
        for (int r = 0; r < 4; r++)
            #pragma unroll
            for (int j = 0; j < 4; j++) { az[r][j] += a[r] * wz[j]; ar[r][j] += a[r] * wr[j]; }
    }

    float Hreg[4][4], rH[4][4];
    #pragma unroll
    for (int r = 0; r < 4; r++)
        #pragma unroll
        for (int j = 0; j < 4; j++) {
            az[r][j] = fast_sigmoid(az[r][j]);
            float rv = fast_sigmoid(ar[r][j]);
            Hreg[r][j] = lds[(128 + c0 + j) * LDST + (r0 + r)];
            rH[r][j] = rv * Hreg[r][j];
        }
    __syncthreads();
    #pragma unroll
    for (int r = 0; r < 4; r++)
        #pragma unroll
        for (int j = 0; j < 4; j++)
            lds[(128 + c0 + j) * LDST + (r0 + r)] = rH[r][j];
    __syncthreads();

    float ah[4][4];
    {
        const float4 bhv = *reinterpret_cast<const float4*>(&bh[c0]);
        float vb[4] = {bhv.x, bhv.y, bhv.z, bhv.w};
        #pragma unroll
        for (int r = 0; r < 4; r++)
            #pragma unroll
            for (int j = 0; j < 4; j++) ah[r][j] = vb[j];
    }
    #pragma unroll 2
    for (int k = 0; k < 256; k++) {
        float4 av = *reinterpret_cast<const float4*>(&lds[k * LDST + r0]);
        float4 wv = *reinterpret_cast<const float4*>(&Wh[(size_t)k * DD + c0]);
        float a[4] = {av.x, av.y, av.z, av.w};
        float w[4] = {wv.x, wv.y, wv.z, wv.w};
        #pragma unroll
        for (int r = 0; r < 4; r++)
            #pragma unroll
            for (int j = 0; j < 4; j++) ah[r][j] += a[r] * w[j];
    }

    #pragma unroll
    for (int r = 0; r < 4; r++) {
        int gn = n0 + r0 + r;
        if (gn < NNODES) {
            #pragma unroll
            for (int j = 0; j < 4; j++) {
                float ht = fast_tanh(ah[r][j]);
                float z = az[r][j];
                out[(size_t)gn * DD + c0 + j] = z * Hreg[r][j] + (1.0f - z) * ht;
            }
        }
    }
}

extern "C" void kernel_launch(void* const* d_in, const int* in_sizes, int n_in,
                              void* d_out, int out_size, void* d_ws, size_t ws_size,
                              hipStream_t stream) {
    const float* x     = (const float*)d_in[0];
    const float* ef    = (const float*)d_in[1];
    const float* Hst   = (const float*)d_in[2];
    const int*   ei    = (const int*)d_in[3];
    const float* Wmsg  = (const float*)d_in[4];
    const float* bconv = (const float*)d_in[5];
    const float* Wskip = (const float*)d_in[6];
    const float* bskip = (const float*)d_in[7];
    const float* Wz    = (const float*)d_in[8];
    const float* bz    = (const float*)d_in[9];
    const float* Wr    = (const float*)d_in[10];
    const float* br    = (const float*)d_in[11];
    const float* Wh    = (const float*)d_in[12];
    const float* bh    = (const float*)d_in[13];
    float* out = (float*)d_out;

    // workspace layout
    float* S   = (float*)d_ws;                               // [N,128]  25.6 MB
    float* T   = S + (size_t)NNODES * DD;                    // [N,32]    6.4 MB
    int*   deg = (int*)(T + (size_t)NNODES * EDD);           // [N]
    int*   off = deg + NNODES;                               // [N+1]
    int*   cur = off + NNODES + 1;                           // [N]
    int2*  csr = (int2*)(cur + NNODES + 1);                  // [E]       6.4 MB

    // zero only the degree array
    hipMemsetAsync(deg, 0, NNODES * sizeof(int), stream);

    int nbE = (NEDGES + 255) / 256;
    count_kernel<<<nbE, 256, 0, stream>>>(ei, deg);
    scan_kernel<<<1, 1024, 0, stream>>>(deg, off, cur);
    fill_kernel<<<nbE, 256, 0, stream>>>(ei, cur, csr);

    int nbA = (NNODES * 64 + 255) / 256;
    aggregate_kernel<<<nbA, 256, 0, stream>>>(x, ef, csr, off, S, T);

    int nb2 = (NNODES + NT - 1) / NT;
    node_kernel<<<nb2, 256, 0, stream>>>(x, Hst, S, T, Wmsg, bconv, Wskip, bskip,
                                         Wz, bz, Wr, br, Wh, bh, out);
}

// Round 3
// 418.293 us; speedup vs baseline: 2.6182x; 1.6676x over previous
//
#include <hip/hip_runtime.h>
#include <hip/hip_bf16.h>

#define NNODES 50000
#define NEDGES 800000
#define DD 128
#define EDD 32

typedef short bfrag __attribute__((ext_vector_type(8)));   // 8 bf16 = 4 VGPRs
typedef float fx4  __attribute__((ext_vector_type(4)));    // MFMA accumulator

// packed-weight slot offsets (in units of 16B slots)
#define PW_CONV 0        // 9 kb * 8 t * 64
#define PW_Z    4608     // 8 * 8 * 64
#define PW_R    8704
#define PW_H    12800
#define PW_TOT  16896

__device__ __forceinline__ unsigned short f2bf(float f) {
    unsigned u = __float_as_uint(f);
    u += 0x7fffu + ((u >> 16) & 1u);      // round-to-nearest-even
    return (unsigned short)(u >> 16);
}
__device__ __forceinline__ float bf2f(unsigned short s) {
    return __uint_as_float(((unsigned)s) << 16);
}
__device__ __forceinline__ float fast_sigmoid(float x) {
    return 1.0f / (1.0f + __expf(-x));
}
__device__ __forceinline__ float fast_tanh(float x) {
    return 1.0f - 2.0f / (__expf(2.0f * x) + 1.0f);
}

// ---------------- CSR build ----------------
__global__ __launch_bounds__(256) void count_kernel(const int* __restrict__ ei,
                                                    int* __restrict__ deg) {
    int e = blockIdx.x * 256 + threadIdx.x;
    if (e < NEDGES) atomicAdd(&deg[ei[NEDGES + e]], 1);
}

__global__ __launch_bounds__(1024) void scan_kernel(const int* __restrict__ deg,
                                                    int* __restrict__ off,
                                                    int* __restrict__ cursor) {
    __shared__ int part[1024];
    const int t = threadIdx.x;
    const int CH = (NNODES + 1023) / 1024;
    const int base = t * CH;
    int s = 0;
    for (int i = 0; i < CH; i++) {
        int idx = base + i;
        if (idx < NNODES) s += deg[idx];
    }
    part[t] = s;
    __syncthreads();
    for (int d = 1; d < 1024; d <<= 1) {
        int v = 0;
        if (t >= d) v = part[t - d];
        __syncthreads();
        if (t >= d) part[t] += v;
        __syncthreads();
    }
    int run = (t == 0) ? 0 : part[t - 1];
    for (int i = 0; i < CH; i++) {
        int idx = base + i;
        if (idx < NNODES) {
            off[idx] = run;
            cursor[idx] = run;
            run += deg[idx];
        }
    }
    if (t == 1023) off[NNODES] = part[1023];
}

__global__ __launch_bounds__(256) void fill_kernel(const int* __restrict__ ei,
                                                   int* __restrict__ cursor,
                                                   int2* __restrict__ csr) {
    int e = blockIdx.x * 256 + threadIdx.x;
    if (e < NEDGES) {
        int dst = ei[NEDGES + e];
        int p = atomicAdd(&cursor[dst], 1);
        csr[p] = make_int2(ei[e], e);
    }
}

// ---------------- gather aggregation: one wave per node ----------------
__global__ __launch_bounds__(256) void aggregate_kernel(
    const float* __restrict__ x, const float* __restrict__ ef,
    const int2* __restrict__ csr, const int* __restrict__ off,
    float* __restrict__ S, float* __restrict__ T)
{
    int n = (int)((blockIdx.x * blockDim.x + threadIdx.x) >> 6);
    int lane = threadIdx.x & 63;
    if (n >= NNODES) return;
    int i0 = off[n], i1 = off[n + 1];
    float2 acc = make_float2(0.0f, 0.0f);
    float accT = 0.0f;
    for (int i = i0; i < i1; i++) {
        int2 ce = csr[i];
        const float2 v = *reinterpret_cast<const float2*>(&x[(size_t)ce.x * DD + lane * 2]);
        acc.x += v.x;
        acc.y += v.y;
        if (lane < EDD) accT += ef[(size_t)ce.y * EDD + lane];
    }
    *reinterpret_cast<float2*>(&S[(size_t)n * DD + lane * 2]) = acc;
    if (lane < EDD) T[(size_t)n * EDD + lane] = accT;
}

// ---------------- weight pre-pack into bf16 fragment layout ----------------
// slot (kb, t, lane): element j = W[kb*32 + (lane>>4)*8 + j][t*16 + (lane&15)]
__global__ __launch_bounds__(256) void pack_weights(
    const float* __restrict__ Wmsg, const float* __restrict__ Wskip,
    const float* __restrict__ Wz, const float* __restrict__ Wr,
    const float* __restrict__ Wh, bfrag* __restrict__ pW)
{
    int id = blockIdx.x * 256 + threadIdx.x;
    if (id >= PW_TOT) return;
    const float* W = nullptr;
    int rem;
    bool conv = false;
    if (id < PW_Z)      { rem = id;           conv = true; }
    else if (id < PW_R) { rem = id - PW_Z;    W = Wz; }
    else if (id < PW_H) { rem = id - PW_R;    W = Wr; }
    else                { rem = id - PW_H;    W = Wh; }
    int kb   = rem >> 9;          // 512 slots per kb (8 t * 64 lanes)
    int t    = (rem >> 6) & 7;
    int lane = rem & 63;
    int col  = t * 16 + (lane & 15);
    int k0   = kb * 32 + ((lane >> 4) << 3);
    bfrag v;
    #pragma unroll
    for (int j = 0; j < 8; j++) {
        int k = k0 + j;
        float w;
        if (conv) w = (k < 160) ? Wmsg[k * DD + col] : Wskip[(k - 160) * DD + col];
        else      w = W[k * DD + col];
        v[j] = (short)f2bf(w);
    }
    pW[id] = v;
}

// ---------------- fused MFMA node kernel ----------------
// 32 nodes/block (2 M-tiles), 4 waves; wave w: m = w&1, n-tiles (w>>1)*4 + 0..3.
// conv A (K=288): kb0-3 = S, kb4 = T, kb5-8 = x.  gates A (K=256): kb0-3 = h
// (aliases lclA), kb4-7 = H / later rH (lclG).
__global__ __launch_bounds__(256) void node_mfma(
    const float* __restrict__ x, const float* __restrict__ H,
    const float* __restrict__ S, const float* __restrict__ T,
    const bfrag* __restrict__ pW,
    const float* __restrict__ bconv, const float* __restrict__ bskip,
    const float* __restrict__ bz, const float* __restrict__ br,
    const float* __restrict__ bh,
    float* __restrict__ out)
{
    __shared__ short lclA[9 * 2 * 64 * 8];   // 18432 B
    __shared__ short lclG[4 * 2 * 64 * 8];   //  8192 B
    const int tid = threadIdx.x;
    const int n0 = blockIdx.x * 32;

    // ---- stage conv A (1152 slots) ----
    for (int s = tid; s < 1152; s += 256) {
        int kb = s >> 7, mm = (s >> 6) & 1, cb = (s >> 4) & 3, r16 = s & 15;
        int row = mm * 16 + r16, gn = n0 + row;
        int k0 = kb * 32 + cb * 8;
        bfrag v;
        if (gn < NNODES) {
            const float* src;
            if (k0 < 128)       src = &S[(size_t)gn * DD + k0];
            else if (k0 < 160)  src = &T[(size_t)gn * EDD + (k0 - 128)];
            else                src = &x[(size_t)gn * DD + (k0 - 160)];
            float4 p0 = *(const float4*)src;
            float4 p1 = *(const float4*)(src + 4);
            v[0] = (short)f2bf(p0.x); v[1] = (short)f2bf(p0.y);
            v[2] = (short)f2bf(p0.z); v[3] = (short)f2bf(p0.w);
            v[4] = (short)f2bf(p1.x); v[5] = (short)f2bf(p1.y);
            v[6] = (short)f2bf(p1.z); v[7] = (short)f2bf(p1.w);
        } else {
            #pragma unroll
            for (int j = 0; j < 8; j++) v[j] = 0;
        }
        *(bfrag*)&lclA[((kb * 2 + mm) * 64 + (r16 | (cb << 4))) * 8] = v;
    }
    // ---- stage H (512 slots) into lclG ----
    for (int s = tid; s < 512; s += 256) {
        int kb = s >> 7, mm = (s >> 6) & 1, cb = (s >> 4) & 3, r16 = s & 15;
        int row = mm * 16 + r16, gn = n0 + row;
        int c0 = kb * 32 + cb * 8;
        bfrag v;
        if (gn < NNODES) {
            const float* src = &H[(size_t)gn * DD + c0];
            float4 p0 = *(const float4*)src;
            float4 p1 = *(const float4*)(src + 4);
            v[0] = (short)f2bf(p0.x); v[1] = (short)f2bf(p0.y);
            v[2] = (short)f2bf(p0.z); v[3] = (short)f2bf(p0.w);
            v[4] = (short)f2bf(p1.x); v[5] = (short)f2bf(p1.y);
            v[6] = (short)f2bf(p1.z); v[7] = (short)f2bf(p1.w);
        } else {
            #pragma unroll
            for (int j = 0; j < 8; j++) v[j] = 0;
        }
        *(bfrag*)&lclG[((kb * 2 + mm) * 64 + (r16 | (cb << 4))) * 8] = v;
    }
    __syncthreads();

    const int w    = tid >> 6;
    const int lane = tid & 63;
    const int m    = w & 1;
    const int ng   = (w >> 1) * 4;       // 0 or 4
    const int lc   = lane & 15;          // col within tile
    const int lr4  = (lane >> 4) * 4;    // row base within tile

    // ---- conv GEMM: 9 kb, 4 n-tiles ----
    fx4 acc[4];
    #pragma unroll
    for (int t = 0; t < 4; t++) {
        int c = (ng + t) * 16 + lc;
        float b = bconv[c] + bskip[c];
        acc[t] = (fx4){b, b, b, b};
    }
    #pragma unroll
    for (int kb = 0; kb < 9; kb++) {
        bfrag a = *(const bfrag*)&lclA[((kb * 2 + m) * 64 + lane) * 8];
        #pragma unroll
        for (int t = 0; t < 4; t++) {
            bfrag b = pW[PW_CONV + (kb * 8 + ng + t) * 64 + lane];
            acc[t] = __builtin_amdgcn_mfma_f32_16x16x32_bf16(a, b, acc[t], 0, 0, 0);
        }
    }
    __syncthreads();   // everyone done reading lclA

    // ---- ReLU -> h, write back as A-fragments into lclA kb0-3 ----
    #pragma unroll
    for (int t = 0; t < 4; t++) {
        int c  = (ng + t) * 16 + lc;     // h column 0..127
        int kb = c >> 5;
        int cb = (c >> 3) & 3;
        int j  = c & 7;
        #pragma unroll
        for (int reg = 0; reg < 4; reg++) {
            int row16 = lr4 + reg;
            float hv = fmaxf(acc[t][reg], 0.0f);
            lclA[((kb * 2 + m) * 64 + (row16 | (cb << 4))) * 8 + j] = (short)f2bf(hv);
        }
    }
    __syncthreads();

    // ---- z, r gates: K=256 (kb0-3 = h in lclA, kb4-7 = H in lclG) ----
    fx4 az[4], ar[4];
    #pragma unroll
    for (int t = 0; t < 4; t++) {
        int c = (ng + t) * 16 + lc;
        float b1 = bz[c], b2 = br[c];
        az[t] = (fx4){b1, b1, b1, b1};
        ar[t] = (fx4){b2, b2, b2, b2};
    }
    #pragma unroll
    for (int kb = 0; kb < 8; kb++) {
        bfrag a = (kb < 4)
            ? *(const bfrag*)&lclA[((kb * 2 + m) * 64 + lane) * 8]
            : *(const bfrag*)&lclG[(((kb - 4) * 2 + m) * 64 + lane) * 8];
        #pragma unroll
        for (int t = 0; t < 4; t++) {
            bfrag wz = pW[PW_Z + (kb * 8 + ng + t) * 64 + lane];
            bfrag wr = pW[PW_R + (kb * 8 + ng + t) * 64 + lane];
            az[t] = __builtin_amdgcn_mfma_f32_16x16x32_bf16(a, wz, az[t], 0, 0, 0);
            ar[t] = __builtin_amdgcn_mfma_f32_16x16x32_bf16(a, wr, ar[t], 0, 0, 0);
        }
    }

    // ---- sigmoid; read H per-lane; rH ----
    float zv[4][4], Hv[4][4], rHv[4][4];
    #pragma unroll
    for (int t = 0; t < 4; t++) {
        int c  = (ng + t) * 16 + lc;
        int kb = c >> 5;
        int cb = (c >> 3) & 3;
        int j  = c & 7;
        #pragma unroll
        for (int reg = 0; reg < 4; reg++) {
            int row16 = lr4 + reg;
            zv[t][reg] = fast_sigmoid(az[t][reg]);
            float rv = fast_sigmoid(ar[t][reg]);
            float hH = bf2f((unsigned short)lclG[((kb * 2 + m) * 64 + (row16 | (cb << 4))) * 8 + j]);
            Hv[t][reg]  = hH;
            rHv[t][reg] = rv * hH;
        }
    }
    __syncthreads();   // all reads of H (frags + scalars) done

    // ---- overwrite lclG with rH fragments ----
    #pragma unroll
    for (int t = 0; t < 4; t++) {
        int c  = (ng + t) * 16 + lc;
        int kb = c >> 5;
        int cb = (c >> 3) & 3;
        int j  = c & 7;
        #pragma unroll
        for (int reg = 0; reg < 4; reg++) {
            int row16 = lr4 + reg;
            lclG[((kb * 2 + m) * 64 + (row16 | (cb << 4))) * 8 + j] = (short)f2bf(rHv[t][reg]);
        }
    }
    __syncthreads();

    // ---- h_tilde: K=256 (h | rH) ----
    fx4 ah[4];
    #pragma unroll
    for (int t = 0; t < 4; t++) {
        int c = (ng + t) * 16 + lc;
        float b = bh[c];
        ah[t] = (fx4){b, b, b, b};
    }
    #pragma unroll
    for (int kb = 0; kb < 8; kb++) {
        bfrag a = (kb < 4)
            ? *(const bfrag*)&lclA[((kb * 2 + m) * 64 + lane) * 8]
            : *(const bfrag*)&lclG[(((kb - 4) * 2 + m) * 64 + lane) * 8];
        #pragma unroll
        for (int t = 0; t < 4; t++) {
            bfrag wh = pW[PW_H + (kb * 8 + ng + t) * 64 + lane];
            ah[t] = __builtin_amdgcn_mfma_f32_16x16x32_bf16(a, wh, ah[t], 0, 0, 0);
        }
    }

    // ---- epilogue: out = z*H + (1-z)*tanh(ah) ----
    #pragma unroll
    for (int reg = 0; reg < 4; reg++) {
        int row = m * 16 + lr4 + reg;
        int gn = n0 + row;
        if (gn < NNODES) {
            #pragma unroll
            for (int t = 0; t < 4; t++) {
                int c = (ng + t) * 16 + lc;
                float ht = fast_tanh(ah[t][reg]);
                float zz = zv[t][reg];
                out[(size_t)gn * DD + c] = zz * Hv[t][reg] + (1.0f - zz) * ht;
            }
        }
    }
}

extern "C" void kernel_launch(void* const* d_in, const int* in_sizes, int n_in,
                              void* d_out, int out_size, void* d_ws, size_t ws_size,
                              hipStream_t stream) {
    const float* x     = (const float*)d_in[0];
    const float* ef    = (const float*)d_in[1];
    const float* Hst   = (const float*)d_in[2];
    const int*   ei    = (const int*)d_in[3];
    const float* Wmsg  = (const float*)d_in[4];
    const float* bconv = (const float*)d_in[5];
    const float* Wskip = (const float*)d_in[6];
    const float* bskip = (const float*)d_in[7];
    const float* Wz    = (const float*)d_in[8];
    const float* bz    = (const float*)d_in[9];
    const float* Wr    = (const float*)d_in[10];
    const float* br    = (const float*)d_in[11];
    const float* Wh    = (const float*)d_in[12];
    const float* bh    = (const float*)d_in[13];
    float* out = (float*)d_out;

    // workspace layout (pW first to keep 16B alignment)
    bfrag* pW  = (bfrag*)d_ws;                               // 270336 B
    float* S   = (float*)((char*)d_ws + PW_TOT * 16);        // [N,128] 25.6 MB
    float* T   = S + (size_t)NNODES * DD;                    // [N,32]   6.4 MB
    int*   deg = (int*)(T + (size_t)NNODES * EDD);           // [N]
    int*   off = deg + NNODES;                               // [N+1]
    int*   cur = off + NNODES + 1;                           // [N+1]
    int2*  csr = (int2*)(cur + NNODES + 1);                  // [E] 6.4 MB

    hipMemsetAsync(deg, 0, NNODES * sizeof(int), stream);

    pack_weights<<<(PW_TOT + 255) / 256, 256, 0, stream>>>(Wmsg, Wskip, Wz, Wr, Wh, pW);

    int nbE = (NEDGES + 255) / 256;
    count_kernel<<<nbE, 256, 0, stream>>>(ei, deg);
    scan_kernel<<<1, 1024, 0, stream>>>(deg, off, cur);
    fill_kernel<<<nbE, 256, 0, stream>>>(ei, cur, csr);

    int nbA = (NNODES * 64 + 255) / 256;
    aggregate_kernel<<<nbA, 256, 0, stream>>>(x, ef, csr, off, S, T);

    int nb2 = (NNODES + 31) / 32;
    node_mfma<<<nb2, 256, 0, stream>>>(x, Hst, S, T, pW, bconv, bskip,
                                       bz, br, bh, out);
}

// Round 5
// 365.076 us; speedup vs baseline: 2.9999x; 1.1458x over previous
//
#include <hip/hip_runtime.h>
#include <hip/hip_bf16.h>

#define NNODES 50000
#define NEDGES 800000
#define DD 128
#define EDD 32

typedef short bfrag __attribute__((ext_vector_type(8)));   // 8 bf16 = 4 VGPRs
typedef float fx4  __attribute__((ext_vector_type(4)));    // MFMA accumulator

// packed-weight slot offsets (in units of 16B slots)
#define PW_CONV 0        // 9 kb * 8 t * 64
#define PW_Z    4608     // 8 * 8 * 64
#define PW_R    8704
#define PW_H    12800
#define PW_TOT  16896

__device__ __forceinline__ unsigned short f2bf(float f) {
    unsigned u = __float_as_uint(f);
    u += 0x7fffu + ((u >> 16) & 1u);      // round-to-nearest-even
    return (unsigned short)(u >> 16);
}
__device__ __forceinline__ float bf2f(unsigned short s) {
    return __uint_as_float(((unsigned)s) << 16);
}
__device__ __forceinline__ float fast_sigmoid(float x) {
    return 1.0f / (1.0f + __expf(-x));
}
__device__ __forceinline__ float fast_tanh(float x) {
    return 1.0f - 2.0f / (__expf(2.0f * x) + 1.0f);
}

// ---------------- CSR build ----------------
__global__ __launch_bounds__(256) void count_kernel(const int* __restrict__ ei,
                                                    int* __restrict__ deg) {
    int e = blockIdx.x * 256 + threadIdx.x;
    if (e < NEDGES) atomicAdd(&deg[ei[NEDGES + e]], 1);
}

__global__ __launch_bounds__(1024) void scan_kernel(const int* __restrict__ deg,
                                                    int* __restrict__ off,
                                                    int* __restrict__ cursor) {
    __shared__ int part[1024];
    const int t = threadIdx.x;
    const int CH = (NNODES + 1023) / 1024;
    const int base = t * CH;
    int s = 0;
    for (int i = 0; i < CH; i++) {
        int idx = base + i;
        if (idx < NNODES) s += deg[idx];
    }
    part[t] = s;
    __syncthreads();
    for (int d = 1; d < 1024; d <<= 1) {
        int v = 0;
        if (t >= d) v = part[t - d];
        __syncthreads();
        if (t >= d) part[t] += v;
        __syncthreads();
    }
    int run = (t == 0) ? 0 : part[t - 1];
    for (int i = 0; i < CH; i++) {
        int idx = base + i;
        if (idx < NNODES) {
            off[idx] = run;
            cursor[idx] = run;
            run += deg[idx];
        }
    }
    if (t == 1023) off[NNODES] = part[1023];
}

__global__ __launch_bounds__(256) void fill_kernel(const int* __restrict__ ei,
                                                   int* __restrict__ cursor,
                                                   long long* __restrict__ csr) {
    int e = blockIdx.x * 256 + threadIdx.x;
    if (e < NEDGES) {
        int dst = ei[NEDGES + e];
        int p = atomicAdd(&cursor[dst], 1);
        // pack (src, eid) into one 64-bit word
        csr[p] = (long long)(unsigned)ei[e] | ((long long)e << 32);
    }
}

// ---------------- gather aggregation: one wave per node, 8-deep MLP ----------------
__global__ __launch_bounds__(256) void aggregate_kernel(
    const float* __restrict__ x, const float* __restrict__ ef,
    const long long* __restrict__ csr, const int* __restrict__ off,
    short* __restrict__ Sb, short* __restrict__ Tb)
{
    int n = (int)((blockIdx.x * blockDim.x + threadIdx.x) >> 6);
    int lane = threadIdx.x & 63;
    if (n >= NNODES) return;
    int i0 = off[n], i1 = off[n + 1];
    float2 acc = make_float2(0.0f, 0.0f);
    float accT = 0.0f;
    int i = i0;
    // main: 8 edges in flight
    for (; i + 8 <= i1; i += 8) {
        long long c[8];
        #pragma unroll
        for (int u = 0; u < 8; u++) c[u] = __builtin_nontemporal_load(&csr[i + u]);
        float2 v[8];
        #pragma unroll
        for (int u = 0; u < 8; u++) {
            int src = (int)(unsigned)c[u];
            v[u] = *reinterpret_cast<const float2*>(&x[(size_t)src * DD + lane * 2]);
        }
        float e[8];
        #pragma unroll
        for (int u = 0; u < 8; u++) {
            int eid = (int)(c[u] >> 32);
            e[u] = (lane < EDD) ? __builtin_nontemporal_load(&ef[(size_t)eid * EDD + lane]) : 0.0f;
        }
        #pragma unroll
        for (int u = 0; u < 8; u++) {
            acc.x += v[u].x; acc.y += v[u].y; accT += e[u];
        }
    }
    // 2-deep cleanup
    for (; i + 2 <= i1; i += 2) {
        long long c0 = __builtin_nontemporal_load(&csr[i]);
        long long c1 = __builtin_nontemporal_load(&csr[i + 1]);
        int s0 = (int)(unsigned)c0, e0i = (int)(c0 >> 32);
        int s1 = (int)(unsigned)c1, e1i = (int)(c1 >> 32);
        float2 v0 = *reinterpret_cast<const float2*>(&x[(size_t)s0 * DD + lane * 2]);
        float2 v1 = *reinterpret_cast<const float2*>(&x[(size_t)s1 * DD + lane * 2]);
        float e0 = (lane < EDD) ? __builtin_nontemporal_load(&ef[(size_t)e0i * EDD + lane]) : 0.0f;
        float e1 = (lane < EDD) ? __builtin_nontemporal_load(&ef[(size_t)e1i * EDD + lane]) : 0.0f;
        acc.x += v0.x; acc.y += v0.y; accT += e0;
        acc.x += v1.x; acc.y += v1.y; accT += e1;
    }
    if (i < i1) {
        long long c0 = __builtin_nontemporal_load(&csr[i]);
        int s0 = (int)(unsigned)c0, e0i = (int)(c0 >> 32);
        float2 v0 = *reinterpret_cast<const float2*>(&x[(size_t)s0 * DD + lane * 2]);
        acc.x += v0.x; acc.y += v0.y;
        if (lane < EDD) accT += __builtin_nontemporal_load(&ef[(size_t)e0i * EDD + lane]);
    }
    // write bf16 (fp32 accumulate, single rounding — identical to staging-side convert)
    unsigned pk = ((unsigned)f2bf(acc.y) << 16) | (unsigned)f2bf(acc.x);
    reinterpret_cast<unsigned*>(Sb)[(size_t)n * 64 + lane] = pk;
    if (lane < EDD)
        reinterpret_cast<unsigned short*>(Tb)[(size_t)n * EDD + lane] = f2bf(accT);
}

// ---------------- weight pre-pack into bf16 fragment layout ----------------
__global__ __launch_bounds__(256) void pack_weights(
    const float* __restrict__ Wmsg, const float* __restrict__ Wskip,
    const float* __restrict__ Wz, const float* __restrict__ Wr,
    const float* __restrict__ Wh, bfrag* __restrict__ pW)
{
    int id = blockIdx.x * 256 + threadIdx.x;
    if (id >= PW_TOT) return;
    const float* W = nullptr;
    int rem;
    bool conv = false;
    if (id < PW_Z)      { rem = id;           conv = true; }
    else if (id < PW_R) { rem = id - PW_Z;    W = Wz; }
    else if (id < PW_H) { rem = id - PW_R;    W = Wr; }
    else                { rem = id - PW_H;    W = Wh; }
    int kb   = rem >> 9;
    int t    = (rem >> 6) & 7;
    int lane = rem & 63;
    int col  = t * 16 + (lane & 15);
    int k0   = kb * 32 + ((lane >> 4) << 3);
    bfrag v;
    #pragma unroll
    for (int j = 0; j < 8; j++) {
        int k = k0 + j;
        float w;
        if (conv) w = (k < 160) ? Wmsg[k * DD + col] : Wskip[(k - 160) * DD + col];
        else      w = W[k * DD + col];
        v[j] = (short)f2bf(w);
    }
    pW[id] = v;
}

// ---------------- fused MFMA node kernel ----------------
__global__ __launch_bounds__(256) void node_mfma(
    const float* __restrict__ x, const float* __restrict__ H,
    const short* __restrict__ Sb, const short* __restrict__ Tb,
    const bfrag* __restrict__ pW,
    const float* __restrict__ bconv, const float* __restrict__ bskip,
    const float* __restrict__ bz, const float* __restrict__ br,
    const float* __restrict__ bh,
    float* __restrict__ out)
{
    __shared__ short lclA[9 * 2 * 64 * 8];   // 18432 B
    __shared__ short lclG[4 * 2 * 64 * 8];   //  8192 B
    const int tid = threadIdx.x;
    const int n0 = blockIdx.x * 32;

    // ---- stage conv A (1152 slots): S,T direct bf16; x converted ----
    for (int s = tid; s < 1152; s += 256) {
        int kb = s >> 7, mm = (s >> 6) & 1, cb = (s >> 4) & 3, r16 = s & 15;
        int row = mm * 16 + r16, gn = n0 + row;
        int k0 = kb * 32 + cb * 8;
        bfrag v;
        if (gn < NNODES) {
            if (k0 < 128) {
                v = *(const bfrag*)&Sb[(size_t)gn * DD + k0];
            } else if (k0 < 160) {
                v = *(const bfrag*)&Tb[(size_t)gn * EDD + (k0 - 128)];
            } else {
                const float* src = &x[(size_t)gn * DD + (k0 - 160)];
                float4 p0 = *(const float4*)src;
                float4 p1 = *(const float4*)(src + 4);
                v[0] = (short)f2bf(p0.x); v[1] = (short)f2bf(p0.y);
                v[2] = (short)f2bf(p0.z); v[3] = (short)f2bf(p0.w);
                v[4] = (short)f2bf(p1.x); v[5] = (short)f2bf(p1.y);
                v[6] = (short)f2bf(p1.z); v[7] = (short)f2bf(p1.w);
            }
        } else {
            #pragma unroll
            for (int j = 0; j < 8; j++) v[j] = 0;
        }
        *(bfrag*)&lclA[((kb * 2 + mm) * 64 + (r16 | (cb << 4))) * 8] = v;
    }
    // ---- stage H (512 slots) into lclG ----
    for (int s = tid; s < 512; s += 256) {
        int kb = s >> 7, mm = (s >> 6) & 1, cb = (s >> 4) & 3, r16 = s & 15;
        int row = mm * 16 + r16, gn = n0 + row;
        int c0 = kb * 32 + cb * 8;
        bfrag v;
        if (gn < NNODES) {
            const float* src = &H[(size_t)gn * DD + c0];
            float4 p0 = *(const float4*)src;
            float4 p1 = *(const float4*)(src + 4);
            v[0] = (short)f2bf(p0.x); v[1] = (short)f2bf(p0.y);
            v[2] = (short)f2bf(p0.z); v[3] = (short)f2bf(p0.w);
            v[4] = (short)f2bf(p1.x); v[5] = (short)f2bf(p1.y);
            v[6] = (short)f2bf(p1.z); v[7] = (short)f2bf(p1.w);
        } else {
            #pragma unroll
            for (int j = 0; j < 8; j++) v[j] = 0;
        }
        *(bfrag*)&lclG[((kb * 2 + mm) * 64 + (r16 | (cb << 4))) * 8] = v;
    }
    __syncthreads();

    const int w    = tid >> 6;
    const int lane = tid & 63;
    const int m    = w & 1;
    const int ng   = (w >> 1) * 4;
    const int lc   = lane & 15;
    const int lr4  = (lane >> 4) * 4;

    // ---- conv GEMM: 9 kb, 4 n-tiles ----
    fx4 acc[4];
    #pragma unroll
    for (int t = 0; t < 4; t++) {
        int c = (ng + t) * 16 + lc;
        float b = bconv[c] + bskip[c];
        acc[t] = (fx4){b, b, b, b};
    }
    #pragma unroll
    for (int kb = 0; kb < 9; kb++) {
        bfrag a = *(const bfrag*)&lclA[((kb * 2 + m) * 64 + lane) * 8];
        #pragma unroll
        for (int t = 0; t < 4; t++) {
            bfrag b = pW[PW_CONV + (kb * 8 + ng + t) * 64 + lane];
            acc[t] = __builtin_amdgcn_mfma_f32_16x16x32_bf16(a, b, acc[t], 0, 0, 0);
        }
    }
    __syncthreads();

    // ---- ReLU -> h, write back as A-fragments into lclA kb0-3 ----
    #pragma unroll
    for (int t = 0; t < 4; t++) {
        int c  = (ng + t) * 16 + lc;
        int kb = c >> 5;
        int cb = (c >> 3) & 3;
        int j  = c & 7;
        #pragma unroll
        for (int reg = 0; reg < 4; reg++) {
            int row16 = lr4 + reg;
            float hv = fmaxf(acc[t][reg], 0.0f);
            lclA[((kb * 2 + m) * 64 + (row16 | (cb << 4))) * 8 + j] = (short)f2bf(hv);
        }
    }
    __syncthreads();

    // ---- z, r gates: K=256 ----
    fx4 az[4], ar[4];
    #pragma unroll
    for (int t = 0; t < 4; t++) {
        int c = (ng + t) * 16 + lc;
        float b1 = bz[c], b2 = br[c];
        az[t] = (fx4){b1, b1, b1, b1};
        ar[t] = (fx4){b2, b2, b2, b2};
    }
    #pragma unroll
    for (int kb = 0; kb < 8; kb++) {
        bfrag a = (kb < 4)
            ? *(const bfrag*)&lclA[((kb * 2 + m) * 64 + lane) * 8]
            : *(const bfrag*)&lclG[(((kb - 4) * 2 + m) * 64 + lane) * 8];
        #pragma unroll
        for (int t = 0; t < 4; t++) {
            bfrag wz = pW[PW_Z + (kb * 8 + ng + t) * 64 + lane];
            bfrag wr = pW[PW_R + (kb * 8 + ng + t) * 64 + lane];
            az[t] = __builtin_amdgcn_mfma_f32_16x16x32_bf16(a, wz, az[t], 0, 0, 0);
            ar[t] = __builtin_amdgcn_mfma_f32_16x16x32_bf16(a, wr, ar[t], 0, 0, 0);
        }
    }

    // ---- sigmoid; read H per-lane; rH ----
    float zv[4][4], Hv[4][4], rHv[4][4];
    #pragma unroll
    for (int t = 0; t < 4; t++) {
        int c  = (ng + t) * 16 + lc;
        int kb = c >> 5;
        int cb = (c >> 3) & 3;
        int j  = c & 7;
        #pragma unroll
        for (int reg = 0; reg < 4; reg++) {
            int row16 = lr4 + reg;
            zv[t][reg] = fast_sigmoid(az[t][reg]);
            float rv = fast_sigmoid(ar[t][reg]);
            float hH = bf2f((unsigned short)lclG[((kb * 2 + m) * 64 + (row16 | (cb << 4))) * 8 + j]);
            Hv[t][reg]  = hH;
            rHv[t][reg] = rv * hH;
        }
    }
    __syncthreads();

    // ---- overwrite lclG with rH fragments ----
    #pragma unroll
    for (int t = 0; t < 4; t++) {
        int c  = (ng + t) * 16 + lc;
        int kb = c >> 5;
        int cb = (c >> 3) & 3;
        int j  = c & 7;
        #pragma unroll
        for (int reg = 0; reg < 4; reg++) {
            int row16 = lr4 + reg;
            lclG[((kb * 2 + m) * 64 + (row16 | (cb << 4))) * 8 + j] = (short)f2bf(rHv[t][reg]);
        }
    }
    __syncthreads();

    // ---- h_tilde: K=256 ----
    fx4 ah[4];
    #pragma unroll
    for (int t = 0; t < 4; t++) {
        int c = (ng + t) * 16 + lc;
        float b = bh[c];
        ah[t] = (fx4){b, b, b, b};
    }
    #pragma unroll
    for (int kb = 0; kb < 8; kb++) {
        bfrag a = (kb < 4)
            ? *(const bfrag*)&lclA[((kb * 2 + m) * 64 + lane) * 8]
            : *(const bfrag*)&lclG[(((kb - 4) * 2 + m) * 64 + lane) * 8];
        #pragma unroll
        for (int t = 0; t < 4; t++) {
            bfrag wh = pW[PW_H + (kb * 8 + ng + t) * 64 + lane];
            ah[t] = __builtin_amdgcn_mfma_f32_16x16x32_bf16(a, wh, ah[t], 0, 0, 0);
        }
    }

    // ---- epilogue ----
    #pragma unroll
    for (int reg = 0; reg < 4; reg++) {
        int row = m * 16 + lr4 + reg;
        int gn = n0 + row;
        if (gn < NNODES) {
            #pragma unroll
            for (int t = 0; t < 4; t++) {
                int c = (ng + t) * 16 + lc;
                float ht = fast_tanh(ah[t][reg]);
                float zz = zv[t][reg];
                out[(size_t)gn * DD + c] = zz * Hv[t][reg] + (1.0f - zz) * ht;
            }
        }
    }
}

extern "C" void kernel_launch(void* const* d_in, const int* in_sizes, int n_in,
                              void* d_out, int out_size, void* d_ws, size_t ws_size,
                              hipStream_t stream) {
    const float* x     = (const float*)d_in[0];
    const float* ef    = (const float*)d_in[1];
    const float* Hst   = (const float*)d_in[2];
    const int*   ei    = (const int*)d_in[3];
    const float* Wmsg  = (const float*)d_in[4];
    const float* bconv = (const float*)d_in[5];
    const float* Wskip = (const float*)d_in[6];
    const float* bskip = (const float*)d_in[7];
    const float* Wz    = (const float*)d_in[8];
    const float* bz    = (const float*)d_in[9];
    const float* Wr    = (const float*)d_in[10];
    const float* br    = (const float*)d_in[11];
    const float* Wh    = (const float*)d_in[12];
    const float* bh    = (const float*)d_in[13];
    float* out = (float*)d_out;

    // workspace layout (16B alignment maintained)
    bfrag* pW  = (bfrag*)d_ws;                               // 270336 B
    short* Sb  = (short*)((char*)d_ws + PW_TOT * 16);        // [N,128] bf16 12.8 MB
    short* Tb  = Sb + (size_t)NNODES * DD;                   // [N,32]  bf16  3.2 MB
    int*   deg = (int*)(Tb + (size_t)NNODES * EDD);          // [N]
    int*   off = deg + NNODES;                               // [N+1]
    int*   cur = off + NNODES + 1;                           // [N+1]
    long long* csr = (long long*)(cur + NNODES + 1);         // [E] 6.4 MB

    (void)hipMemsetAsync(deg, 0, NNODES * sizeof(int), stream);

    pack_weights<<<(PW_TOT + 255) / 256, 256, 0, stream>>>(Wmsg, Wskip, Wz, Wr, Wh, pW);

    int nbE = (NEDGES + 255) / 256;
    count_kernel<<<nbE, 256, 0, stream>>>(ei, deg);
    scan_kernel<<<1, 1024, 0, stream>>>(deg, off, cur);
    fill_kernel<<<nbE, 256, 0, stream>>>(ei, cur, csr);

    int nbA = (NNODES * 64 + 255) / 256;
    aggregate_kernel<<<nbA, 256, 0, stream>>>(x, ef, csr, off, Sb, Tb);

    int nb2 = (NNODES + 31) / 32;
    node_mfma<<<nb2, 256, 0, stream>>>(x, Hst, Sb, Tb, pW, bconv, bskip,
                                       bz, br, bh, out);
}

// Round 6
// 245.311 us; speedup vs baseline: 4.4644x; 1.4882x over previous
//
#include <hip/hip_runtime.h>
#include <hip/hip_bf16.h>

#define NNODES 50000
#define NEDGES 800000
#define DD 128
#define EDD 32

#define SNB ((NNODES + 255) / 256)   // 196 scan blocks

typedef short bfrag __attribute__((ext_vector_type(8)));   // 8 bf16 = 4 VGPRs
typedef float fx4  __attribute__((ext_vector_type(4)));    // MFMA accumulator

// packed-weight slot offsets (in units of 16B slots)
#define PW_CONV 0        // 9 kb * 8 t * 64
#define PW_Z    4608     // 8 * 8 * 64
#define PW_R    8704
#define PW_H    12800
#define PW_TOT  16896

__device__ __forceinline__ unsigned short f2bf(float f) {
    unsigned u = __float_as_uint(f);
    u += 0x7fffu + ((u >> 16) & 1u);      // round-to-nearest-even
    return (unsigned short)(u >> 16);
}
__device__ __forceinline__ float bf2f(unsigned short s) {
    return __uint_as_float(((unsigned)s) << 16);
}
__device__ __forceinline__ float fast_sigmoid(float x) {
    return 1.0f / (1.0f + __expf(-x));
}
__device__ __forceinline__ float fast_tanh(float x) {
    return 1.0f - 2.0f / (__expf(2.0f * x) + 1.0f);
}

// ---------------- CSR build ----------------
__global__ __launch_bounds__(256) void count_kernel(const int* __restrict__ ei,
                                                    int* __restrict__ deg) {
    int e = blockIdx.x * 256 + threadIdx.x;
    if (e < NEDGES) atomicAdd(&deg[ei[NEDGES + e]], 1);
}

// hierarchical scan, phase 1: per-block (256-elem) reduce
__global__ __launch_bounds__(256) void scan_reduce(const int* __restrict__ deg,
                                                   int* __restrict__ bsum) {
    __shared__ int s[256];
    int t = threadIdx.x;
    int i = blockIdx.x * 256 + t;
    s[t] = (i < NNODES) ? deg[i] : 0;
    __syncthreads();
    for (int d = 128; d > 0; d >>= 1) {
        if (t < d) s[t] += s[t + d];
        __syncthreads();
    }
    if (t == 0) bsum[blockIdx.x] = s[0];
}

// phase 2: exclusive scan of the 196 block sums (single 256-thread block)
__global__ __launch_bounds__(256) void scan_bsum(int* __restrict__ bsum,
                                                 int* __restrict__ off) {
    __shared__ int s[256];
    int t = threadIdx.x;
    int v = (t < SNB) ? bsum[t] : 0;
    s[t] = v;
    __syncthreads();
    for (int d = 1; d < 256; d <<= 1) {
        int u = (t >= d) ? s[t - d] : 0;
        __syncthreads();
        s[t] += u;
        __syncthreads();
    }
    if (t < SNB) bsum[t] = s[t] - v;      // exclusive base per block
    if (t == 255) off[NNODES] = s[255];   // total = NEDGES
}

// phase 3: per-block exclusive scan + base, write off & cursor
__global__ __launch_bounds__(256) void scan_final(const int* __restrict__ deg,
                                                  const int* __restrict__ bsum,
                                                  int* __restrict__ off,
                                                  int* __restrict__ cursor) {
    __shared__ int s[256];
    int t = threadIdx.x;
    int i = blockIdx.x * 256 + t;
    int v = (i < NNODES) ? deg[i] : 0;
    s[t] = v;
    __syncthreads();
    for (int d = 1; d < 256; d <<= 1) {
        int u = (t >= d) ? s[t - d] : 0;
        __syncthreads();
        s[t] += u;
        __syncthreads();
    }
    if (i < NNODES) {
        int e = bsum[blockIdx.x] + s[t] - v;
        off[i] = e;
        cursor[i] = e;
    }
}

__global__ __launch_bounds__(256) void fill_kernel(const int* __restrict__ ei,
                                                   int* __restrict__ cursor,
                                                   long long* __restrict__ csr) {
    int e = blockIdx.x * 256 + threadIdx.x;
    if (e < NEDGES) {
        int dst = ei[NEDGES + e];
        int p = atomicAdd(&cursor[dst], 1);
        csr[p] = (long long)(unsigned)ei[e] | ((long long)e << 32);
    }
}

// ---------------- gather aggregation: one wave per node, 8-deep MLP ----------------
__global__ __launch_bounds__(256) void aggregate_kernel(
    const float* __restrict__ x, const float* __restrict__ ef,
    const long long* __restrict__ csr, const int* __restrict__ off,
    short* __restrict__ Sb, short* __restrict__ Tb)
{
    int n = (int)((blockIdx.x * blockDim.x + threadIdx.x) >> 6);
    int lane = threadIdx.x & 63;
    if (n >= NNODES) return;
    int i0 = off[n], i1 = off[n + 1];
    float2 acc = make_float2(0.0f, 0.0f);
    float accT = 0.0f;
    int i = i0;
    for (; i + 8 <= i1; i += 8) {
        long long c[8];
        #pragma unroll
        for (int u = 0; u < 8; u++) c[u] = __builtin_nontemporal_load(&csr[i + u]);
        float2 v[8];
        #pragma unroll
        for (int u = 0; u < 8; u++) {
            int src = (int)(unsigned)c[u];
            v[u] = *reinterpret_cast<const float2*>(&x[(size_t)src * DD + lane * 2]);
        }
        float e[8];
        #pragma unroll
        for (int u = 0; u < 8; u++) {
            int eid = (int)(c[u] >> 32);
            e[u] = (lane < EDD) ? __builtin_nontemporal_load(&ef[(size_t)eid * EDD + lane]) : 0.0f;
        }
        #pragma unroll
        for (int u = 0; u < 8; u++) {
            acc.x += v[u].x; acc.y += v[u].y; accT += e[u];
        }
    }
    for (; i + 2 <= i1; i += 2) {
        long long c0 = __builtin_nontemporal_load(&csr[i]);
        long long c1 = __builtin_nontemporal_load(&csr[i + 1]);
        int s0 = (int)(unsigned)c0, e0i = (int)(c0 >> 32);
        int s1 = (int)(unsigned)c1, e1i = (int)(c1 >> 32);
        float2 v0 = *reinterpret_cast<const float2*>(&x[(size_t)s0 * DD + lane * 2]);
        float2 v1 = *reinterpret_cast<const float2*>(&x[(size_t)s1 * DD + lane * 2]);
        float e0 = (lane < EDD) ? __builtin_nontemporal_load(&ef[(size_t)e0i * EDD + lane]) : 0.0f;
        float e1 = (lane < EDD) ? __builtin_nontemporal_load(&ef[(size_t)e1i * EDD + lane]) : 0.0f;
        acc.x += v0.x; acc.y += v0.y; accT += e0;
        acc.x += v1.x; acc.y += v1.y; accT += e1;
    }
    if (i < i1) {
        long long c0 = __builtin_nontemporal_load(&csr[i]);
        int s0 = (int)(unsigned)c0, e0i = (int)(c0 >> 32);
        float2 v0 = *reinterpret_cast<const float2*>(&x[(size_t)s0 * DD + lane * 2]);
        acc.x += v0.x; acc.y += v0.y;
        if (lane < EDD) accT += __builtin_nontemporal_load(&ef[(size_t)e0i * EDD + lane]);
    }
    unsigned pk = ((unsigned)f2bf(acc.y) << 16) | (unsigned)f2bf(acc.x);
    reinterpret_cast<unsigned*>(Sb)[(size_t)n * 64 + lane] = pk;
    if (lane < EDD)
        reinterpret_cast<unsigned short*>(Tb)[(size_t)n * EDD + lane] = f2bf(accT);
}

// ---------------- weight pre-pack into bf16 fragment layout ----------------
__global__ __launch_bounds__(256) void pack_weights(
    const float* __restrict__ Wmsg, const float* __restrict__ Wskip,
    const float* __restrict__ Wz, const float* __restrict__ Wr,
    const float* __restrict__ Wh, bfrag* __restrict__ pW)
{
    int id = blockIdx.x * 256 + threadIdx.x;
    if (id >= PW_TOT) return;
    const float* W = nullptr;
    int rem;
    bool conv = false;
    if (id < PW_Z)      { rem = id;           conv = true; }
    else if (id < PW_R) { rem = id - PW_Z;    W = Wz; }
    else if (id < PW_H) { rem = id - PW_R;    W = Wr; }
    else                { rem = id - PW_H;    W = Wh; }
    int kb   = rem >> 9;
    int t    = (rem >> 6) & 7;
    int lane = rem & 63;
    int col  = t * 16 + (lane & 15);
    int k0   = kb * 32 + ((lane >> 4) << 3);
    bfrag v;
    #pragma unroll
    for (int j = 0; j < 8; j++) {
        int k = k0 + j;
        float w;
        if (conv) w = (k < 160) ? Wmsg[k * DD + col] : Wskip[(k - 160) * DD + col];
        else      w = W[k * DD + col];
        v[j] = (short)f2bf(w);
    }
    pW[id] = v;
}

// ---------------- fused MFMA node kernel ----------------
__global__ __launch_bounds__(256) void node_mfma(
    const float* __restrict__ x, const float* __restrict__ H,
    const short* __restrict__ Sb, const short* __restrict__ Tb,
    const bfrag* __restrict__ pW,
    const float* __restrict__ bconv, const float* __restrict__ bskip,
    const float* __restrict__ bz, const float* __restrict__ br,
    const float* __restrict__ bh,
    float* __restrict__ out)
{
    __shared__ short lclA[9 * 2 * 64 * 8];   // 18432 B
    __shared__ short lclG[4 * 2 * 64 * 8];   //  8192 B
    const int tid = threadIdx.x;
    const int n0 = blockIdx.x * 32;

    for (int s = tid; s < 1152; s += 256) {
        int kb = s >> 7, mm = (s >> 6) & 1, cb = (s >> 4) & 3, r16 = s & 15;
        int row = mm * 16 + r16, gn = n0 + row;
        int k0 = kb * 32 + cb * 8;
        bfrag v;
        if (gn < NNODES) {
            if (k0 < 128) {
                v = *(const bfrag*)&Sb[(size_t)gn * DD + k0];
            } else if (k0 < 160) {
                v = *(const bfrag*)&Tb[(size_t)gn * EDD + (k0 - 128)];
            } else {
                const float* src = &x[(size_t)gn * DD + (k0 - 160)];
                float4 p0 = *(const float4*)src;
                float4 p1 = *(const float4*)(src + 4);
                v[0] = (short)f2bf(p0.x); v[1] = (short)f2bf(p0.y);
                v[2] = (short)f2bf(p0.z); v[3] = (short)f2bf(p0.w);
                v[4] = (short)f2bf(p1.x); v[5] = (short)f2bf(p1.y);
                v[6] = (short)f2bf(p1.z); v[7] = (short)f2bf(p1.w);
            }
        } else {
            #pragma unroll
            for (int j = 0; j < 8; j++) v[j] = 0;
        }
        *(bfrag*)&lclA[((kb * 2 + mm) * 64 + (r16 | (cb << 4))) * 8] = v;
    }
    for (int s = tid; s < 512; s += 256) {
        int kb = s >> 7, mm = (s >> 6) & 1, cb = (s >> 4) & 3, r16 = s & 15;
        int row = mm * 16 + r16, gn = n0 + row;
        int c0 = kb * 32 + cb * 8;
        bfrag v;
        if (gn < NNODES) {
            const float* src = &H[(size_t)gn * DD + c0];
            float4 p0 = *(const float4*)src;
            float4 p1 = *(const float4*)(src + 4);
            v[0] = (short)f2bf(p0.x); v[1] = (short)f2bf(p0.y);
            v[2] = (short)f2bf(p0.z); v[3] = (short)f2bf(p0.w);
            v[4] = (short)f2bf(p1.x); v[5] = (short)f2bf(p1.y);
            v[6] = (short)f2bf(p1.z); v[7] = (short)f2bf(p1.w);
        } else {
            #pragma unroll
            for (int j = 0; j < 8; j++) v[j] = 0;
        }
        *(bfrag*)&lclG[((kb * 2 + mm) * 64 + (r16 | (cb << 4))) * 8] = v;
    }
    __syncthreads();

    const int w    = tid >> 6;
    const int lane = tid & 63;
    const int m    = w & 1;
    const int ng   = (w >> 1) * 4;
    const int lc   = lane & 15;
    const int lr4  = (lane >> 4) * 4;

    fx4 acc[4];
    #pragma unroll
    for (int t = 0; t < 4; t++) {
        int c = (ng + t) * 16 + lc;
        float b = bconv[c] + bskip[c];
        acc[t] = (fx4){b, b, b, b};
    }
    #pragma unroll
    for (int kb = 0; kb < 9; kb++) {
        bfrag a = *(const bfrag*)&lclA[((kb * 2 + m) * 64 + lane) * 8];
        #pragma unroll
        for (int t = 0; t < 4; t++) {
            bfrag b = pW[PW_CONV + (kb * 8 + ng + t) * 64 + lane];
            acc[t] = __builtin_amdgcn_mfma_f32_16x16x32_bf16(a, b, acc[t], 0, 0, 0);
        }
    }
    __syncthreads();

    #pragma unroll
    for (int t = 0; t < 4; t++) {
        int c  = (ng + t) * 16 + lc;
        int kb = c >> 5;
        int cb = (c >> 3) & 3;
        int j  = c & 7;
        #pragma unroll
        for (int reg = 0; reg < 4; reg++) {
            int row16 = lr4 + reg;
            float hv = fmaxf(acc[t][reg], 0.0f);
            lclA[((kb * 2 + m) * 64 + (row16 | (cb << 4))) * 8 + j] = (short)f2bf(hv);
        }
    }
    __syncthreads();

    fx4 az[4], ar[4];
    #pragma unroll
    for (int t = 0; t < 4; t++) {
        int c = (ng + t) * 16 + lc;
        float b1 = bz[c], b2 = br[c];
        az[t] = (fx4){b1, b1, b1, b1};
        ar[t] = (fx4){b2, b2, b2, b2};
    }
    #pragma unroll
    for (int kb = 0; kb < 8; kb++) {
        bfrag a = (kb < 4)
            ? *(const bfrag*)&lclA[((kb * 2 + m) * 64 + lane) * 8]
            : *(const bfrag*)&lclG[(((kb - 4) * 2 + m) * 64 + lane) * 8];
        #pragma unroll
        for (int t = 0; t < 4; t++) {
            bfrag wz = pW[PW_Z + (kb * 8 + ng + t) * 64 + lane];
            bfrag wr = pW[PW_R + (kb * 8 + ng + t) * 64 + lane];
            az[t] = __builtin_amdgcn_mfma_f32_16x16x32_bf16(a, wz, az[t], 0, 0, 0);
            ar[t] = __builtin_amdgcn_mfma_f32_16x16x32_bf16(a, wr, ar[t], 0, 0, 0);
        }
    }

    float zv[4][4], Hv[4][4], rHv[4][4];
    #pragma unroll
    for (int t = 0; t < 4; t++) {
        int c  = (ng + t) * 16 + lc;
        int kb = c >> 5;
        int cb = (c >> 3) & 3;
        int j  = c & 7;
        #pragma unroll
        for (int reg = 0; reg < 4; reg++) {
            int row16 = lr4 + reg;
            zv[t][reg] = fast_sigmoid(az[t][reg]);
            float rv = fast_sigmoid(ar[t][reg]);
            float hH = bf2f((unsigned short)lclG[((kb * 2 + m) * 64 + (row16 | (cb << 4))) * 8 + j]);
            Hv[t][reg]  = hH;
            rHv[t][reg] = rv * hH;
        }
    }
    __syncthreads();

    #pragma unroll
    for (int t = 0; t < 4; t++) {
        int c  = (ng + t) * 16 + lc;
        int kb = c >> 5;
        int cb = (c >> 3) & 3;
        int j  = c & 7;
        #pragma unroll
        for (int reg = 0; reg < 4; reg++) {
            int row16 = lr4 + reg;
            lclG[((kb * 2 + m) * 64 + (row16 | (cb << 4))) * 8 + j] = (short)f2bf(rHv[t][reg]);
        }
    }
    __syncthreads();

    fx4 ah[4];
    #pragma unroll
    for (int t = 0; t < 4; t++) {
        int c = (ng + t) * 16 + lc;
        float b = bh[c];
        ah[t] = (fx4){b, b, b, b};
    }
    #pragma unroll
    for (int kb = 0; kb < 8; kb++) {
        bfrag a = (kb < 4)
            ? *(const bfrag*)&lclA[((kb * 2 + m) * 64 + lane) * 8]
            : *(const bfrag*)&lclG[(((kb - 4) * 2 + m) * 64 + lane) * 8];
        #pragma unroll
        for (int t = 0; t < 4; t++) {
            bfrag wh = pW[PW_H + (kb * 8 + ng + t) * 64 + lane];
            ah[t] = __builtin_amdgcn_mfma_f32_16x16x32_bf16(a, wh, ah[t], 0, 0, 0);
        }
    }

    #pragma unroll
    for (int reg = 0; reg < 4; reg++) {
        int row = m * 16 + lr4 + reg;
        int gn = n0 + row;
        if (gn < NNODES) {
            #pragma unroll
            for (int t = 0; t < 4; t++) {
                int c = (ng + t) * 16 + lc;
                float ht = fast_tanh(ah[t][reg]);
                float zz = zv[t][reg];
                out[(size_t)gn * DD + c] = zz * Hv[t][reg] + (1.0f - zz) * ht;
            }
        }
    }
}

extern "C" void kernel_launch(void* const* d_in, const int* in_sizes, int n_in,
                              void* d_out, int out_size, void* d_ws, size_t ws_size,
                              hipStream_t stream) {
    const float* x     = (const float*)d_in[0];
    const float* ef    = (const float*)d_in[1];
    const float* Hst   = (const float*)d_in[2];
    const int*   ei    = (const int*)d_in[3];
    const float* Wmsg  = (const float*)d_in[4];
    const float* bconv = (const float*)d_in[5];
    const float* Wskip = (const float*)d_in[6];
    const float* bskip = (const float*)d_in[7];
    const float* Wz    = (const float*)d_in[8];
    const float* bz    = (const float*)d_in[9];
    const float* Wr    = (const float*)d_in[10];
    const float* br    = (const float*)d_in[11];
    const float* Wh    = (const float*)d_in[12];
    const float* bh    = (const float*)d_in[13];
    float* out = (float*)d_out;

    // workspace layout (16B alignment maintained)
    bfrag* pW  = (bfrag*)d_ws;                               // 270336 B
    short* Sb  = (short*)((char*)d_ws + PW_TOT * 16);        // [N,128] bf16 12.8 MB
    short* Tb  = Sb + (size_t)NNODES * DD;                   // [N,32]  bf16  3.2 MB
    int*   deg = (int*)(Tb + (size_t)NNODES * EDD);          // [N]
    int*   off = deg + NNODES;                               // [N+1]
    int*   cur = off + NNODES + 1;                           // [N+1]
    int*   bsum = cur + NNODES + 1;                          // [256] (pad to even)
    long long* csr = (long long*)(bsum + 256);               // [E] 6.4 MB (8B-aligned)

    (void)hipMemsetAsync(deg, 0, NNODES * sizeof(int), stream);

    pack_weights<<<(PW_TOT + 255) / 256, 256, 0, stream>>>(Wmsg, Wskip, Wz, Wr, Wh, pW);

    int nbE = (NEDGES + 255) / 256;
    count_kernel<<<nbE, 256, 0, stream>>>(ei, deg);
    scan_reduce<<<SNB, 256, 0, stream>>>(deg, bsum);
    scan_bsum<<<1, 256, 0, stream>>>(bsum, off);
    scan_final<<<SNB, 256, 0, stream>>>(deg, bsum, off, cur);
    fill_kernel<<<nbE, 256, 0, stream>>>(ei, cur, csr);

    int nbA = (NNODES * 64 + 255) / 256;
    aggregate_kernel<<<nbA, 256, 0, stream>>>(x, ef, csr, off, Sb, Tb);

    int nb2 = (NNODES + 31) / 32;
    node_mfma<<<nb2, 256, 0, stream>>>(x, Hst, Sb, Tb, pW, bconv, bskip,
                                       bz, br, bh, out);
}